// Round 1
// baseline (630.367 us; speedup 1.0000x reference)
//
#include <hip/hip_runtime.h>
#include <hip/hip_bf16.h>

#define HEADS 4
#define OUT_C 64
#define CH 256           // HEADS*OUT_C == IN_C == 256
#define NEG_SLOPE 0.2f

// ---------------------------------------------------------------------------
// K0: init degree array (1 per node, accounting for the self loop)
// ---------------------------------------------------------------------------
__global__ __launch_bounds__(256) void init_deg_kernel(int* __restrict__ cursor, int N) {
    int i = blockIdx.x * 256 + threadIdx.x;
    if (i < N) cursor[i] = 1;
}

// ---------------------------------------------------------------------------
// K1: count in-degree per dst
// ---------------------------------------------------------------------------
__global__ __launch_bounds__(256) void count_kernel(const int* __restrict__ ei,
                                                    int* __restrict__ cursor,
                                                    int N, int E) {
    int e = blockIdx.x * 256 + threadIdx.x;
    if (e < E) {
        int d = ei[E + e];
        if ((unsigned)d < (unsigned)N) atomicAdd(&cursor[d], 1);
    }
}

// ---------------------------------------------------------------------------
// K2: single-block exclusive scan of degrees -> rowptr, and cursor=rowptr copy
// cursor array doubles as deg input (overwritten in place).
// ---------------------------------------------------------------------------
__global__ __launch_bounds__(256) void scan_kernel(int* __restrict__ cursor,
                                                   int* __restrict__ rowptr,
                                                   int N) {
    __shared__ int wsums[4];
    __shared__ int carry;
    int tid = threadIdx.x;
    if (tid == 0) carry = 0;
    __syncthreads();
    int nchunk = (N + 255) / 256;
    for (int c = 0; c < nchunk; ++c) {
        int i = c * 256 + tid;
        int v = (i < N) ? cursor[i] : 0;
        int lane = tid & 63;
        int incl = v;
        #pragma unroll
        for (int o = 1; o < 64; o <<= 1) {
            int t = __shfl_up(incl, o, 64);
            if (lane >= o) incl += t;
        }
        int w = tid >> 6;
        if (lane == 63) wsums[w] = incl;
        __syncthreads();
        int woff = 0;
        if (w > 0) woff += wsums[0];
        if (w > 1) woff += wsums[1];
        if (w > 2) woff += wsums[2];
        int excl = carry + woff + incl - v;
        if (i < N) { rowptr[i] = excl; cursor[i] = excl; }
        __syncthreads();
        if (tid == 0) carry += wsums[0] + wsums[1] + wsums[2] + wsums[3];
        __syncthreads();
    }
    if (tid == 0) rowptr[N] = carry;
}

// ---------------------------------------------------------------------------
// K3: scatter edges (and self loops) into CSR src lists
// ---------------------------------------------------------------------------
__global__ __launch_bounds__(256) void scatter_kernel(const int* __restrict__ ei,
                                                      int* __restrict__ cursor,
                                                      int* __restrict__ srclist,
                                                      int N, int E) {
    int e = blockIdx.x * 256 + threadIdx.x;
    if (e < E) {
        int s = ei[e];
        int d = ei[E + e];
        if ((unsigned)s < (unsigned)N && (unsigned)d < (unsigned)N) {
            int pos = atomicAdd(&cursor[d], 1);
            srclist[pos] = s;
        }
    } else if (e < E + N) {
        int n = e - E;
        int pos = atomicAdd(&cursor[n], 1);
        srclist[pos] = n;
    }
}

// ---------------------------------------------------------------------------
// K4: SGEMM  h[M,256] = x[M,256] @ W[256,256]   (fp32, LDS-tiled)
// 64x64 tile per 256-thread block, 4x4 microtile per thread, BK=16.
// ---------------------------------------------------------------------------
#define BM 64
#define BN 64
#define BK 16
__global__ __launch_bounds__(256) void gemm_kernel(const float* __restrict__ A,
                                                   const float* __restrict__ B,
                                                   float* __restrict__ C,
                                                   int M) {
    __shared__ float As[BK][BM + 4];   // pad to 68 floats: 16B-aligned float4 rows
    __shared__ float Bs[BK][BN];
    int tid = threadIdx.x;
    int tx = tid & 15;          // 16 cols of threads
    int ty = tid >> 4;          // 16 rows of threads
    int row0 = blockIdx.x * BM;
    int col0 = blockIdx.y * BN;

    float acc[4][4];
    #pragma unroll
    for (int i = 0; i < 4; ++i)
        #pragma unroll
        for (int j = 0; j < 4; ++j) acc[i][j] = 0.f;

    for (int k0 = 0; k0 < CH; k0 += BK) {
        // load A tile (BM x BK), store transposed As[k][r]
        #pragma unroll
        for (int i = tid; i < BM * BK; i += 256) {
            int r = i >> 4;          // /BK
            int k = i & 15;          // %BK
            int gr = row0 + r;
            As[k][r] = (gr < M) ? A[(size_t)gr * CH + k0 + k] : 0.f;
        }
        // load B tile (BK x BN)
        #pragma unroll
        for (int i = tid; i < BK * BN; i += 256) {
            int k = i >> 6;          // /BN
            int cc = i & 63;         // %BN
            Bs[k][cc] = B[(size_t)(k0 + k) * CH + col0 + cc];
        }
        __syncthreads();
        #pragma unroll
        for (int k = 0; k < BK; ++k) {
            float4 a4 = *reinterpret_cast<const float4*>(&As[k][ty * 4]);
            float4 b4 = *reinterpret_cast<const float4*>(&Bs[k][tx * 4]);
            float a[4] = {a4.x, a4.y, a4.z, a4.w};
            float b[4] = {b4.x, b4.y, b4.z, b4.w};
            #pragma unroll
            for (int i = 0; i < 4; ++i)
                #pragma unroll
                for (int j = 0; j < 4; ++j) acc[i][j] += a[i] * b[j];
        }
        __syncthreads();
    }

    #pragma unroll
    for (int i = 0; i < 4; ++i) {
        int gr = row0 + ty * 4 + i;
        if (gr < M) {
            float4 v = make_float4(acc[i][0], acc[i][1], acc[i][2], acc[i][3]);
            *reinterpret_cast<float4*>(&C[(size_t)gr * CH + col0 + tx * 4]) = v;
        }
    }
}

// ---------------------------------------------------------------------------
// K5: attention scores  a_src[n,h] = <h[n,h,:], att_src[h,:]>  (same for dst)
// one block per node; wave w handles head w; lane = channel.
// ---------------------------------------------------------------------------
__global__ __launch_bounds__(256) void attn_kernel(const float* __restrict__ h,
                                                   const float* __restrict__ att_src,
                                                   const float* __restrict__ att_dst,
                                                   float* __restrict__ a_src,
                                                   float* __restrict__ a_dst,
                                                   int N) {
    int n = blockIdx.x;
    int tid = threadIdx.x;
    int hd = tid >> 6;
    int lane = tid & 63;
    float v = h[(size_t)n * CH + tid];
    float s = v * att_src[tid];
    float d = v * att_dst[tid];
    #pragma unroll
    for (int o = 32; o > 0; o >>= 1) {
        s += __shfl_xor(s, o, 64);
        d += __shfl_xor(d, o, 64);
    }
    if (lane == 0) {
        a_src[n * HEADS + hd] = s;
        a_dst[n * HEADS + hd] = d;
    }
}

// ---------------------------------------------------------------------------
// K6: aggregate. One block per dst node, thread = output channel.
// denominators accumulate redundantly per lane (identical across a head's 64
// lanes) -> no atomics anywhere, single coalesced write of the output row.
// exp(alpha) without max-subtraction: |alpha| < ~15 so fp32 exp is safe and
// the softmax ratio is mathematically identical.
// ---------------------------------------------------------------------------
__global__ __launch_bounds__(256) void aggregate_kernel(const float* __restrict__ h,
                                                        const float* __restrict__ a_src,
                                                        const float* __restrict__ a_dst,
                                                        const int* __restrict__ rowptr,
                                                        const int* __restrict__ srclist,
                                                        const float* __restrict__ bias,
                                                        float* __restrict__ out,
                                                        int N) {
    int n = blockIdx.x;
    int tid = threadIdx.x;
    int hd = tid >> 6;
    int start = rowptr[n];
    int end = rowptr[n + 1];
    float ad = a_dst[n * HEADS + hd];
    float acc = 0.f;
    float denom = 0.f;
    for (int i = start; i < end; ++i) {
        int s = srclist[i];
        float as = a_src[s * HEADS + hd];
        float alpha = as + ad;
        alpha = (alpha >= 0.f) ? alpha : NEG_SLOPE * alpha;
        float ex = __expf(alpha);
        denom += ex;
        acc += ex * h[(size_t)s * CH + tid];
    }
    out[(size_t)n * CH + tid] = acc / (denom + 1e-16f) + bias[tid];
}

// ---------------------------------------------------------------------------
extern "C" void kernel_launch(void* const* d_in, const int* in_sizes, int n_in,
                              void* d_out, int out_size, void* d_ws, size_t ws_size,
                              hipStream_t stream) {
    const float* x       = (const float*)d_in[0];
    const int*   ei      = (const int*)d_in[1];
    const float* W       = (const float*)d_in[2];
    const float* att_src = (const float*)d_in[3];
    const float* att_dst = (const float*)d_in[4];
    const float* bias    = (const float*)d_in[5];
    float* out = (float*)d_out;

    int N = in_sizes[0] / CH;      // 50000
    int E = in_sizes[1] / 2;       // 800000

    auto align = [](size_t v) { return (v + 255) & ~(size_t)255; };
    char* ws = (char*)d_ws;
    size_t off = 0;
    float* h      = (float*)(ws + off); off = align(off + (size_t)N * CH * 4);
    float* a_src  = (float*)(ws + off); off = align(off + (size_t)N * HEADS * 4);
    float* a_dst  = (float*)(ws + off); off = align(off + (size_t)N * HEADS * 4);
    int*   rowptr = (int*)(ws + off);   off = align(off + (size_t)(N + 1) * 4);
    int*   cursor = (int*)(ws + off);   off = align(off + (size_t)N * 4);
    int*   srclist= (int*)(ws + off);   off = align(off + (size_t)(E + N) * 4);

    // CSR build
    init_deg_kernel<<<(N + 255) / 256, 256, 0, stream>>>(cursor, N);
    count_kernel<<<(E + 255) / 256, 256, 0, stream>>>(ei, cursor, N, E);
    scan_kernel<<<1, 256, 0, stream>>>(cursor, rowptr, N);
    scatter_kernel<<<(E + N + 255) / 256, 256, 0, stream>>>(ei, cursor, srclist, N, E);

    // dense phase
    dim3 ggrid((N + BM - 1) / BM, CH / BN);
    gemm_kernel<<<ggrid, 256, 0, stream>>>(x, W, h, N);
    attn_kernel<<<N, 256, 0, stream>>>(h, att_src, att_dst, a_src, a_dst, N);

    // gather-aggregate
    aggregate_kernel<<<N, 256, 0, stream>>>(h, a_src, a_dst, rowptr, srclist, bias, out, N);
}

// Round 2
// 476.522 us; speedup vs baseline: 1.3228x; 1.3228x over previous
//
#include <hip/hip_runtime.h>
#include <hip/hip_bf16.h>

#define HEADS 4
#define OUT_C 64
#define CH 256           // HEADS*OUT_C == IN_C == 256
#define NEG_SLOPE 0.2f
#define MAXDEG 128       // edge-chunk staged in LDS per dst node

__device__ inline float bf2f(unsigned short u) {
    return __uint_as_float(((unsigned)u) << 16);
}
__device__ inline unsigned short f2bf(float f) {
    __hip_bfloat16 b = __float2bfloat16(f);   // RNE
    return *reinterpret_cast<unsigned short*>(&b);
}

// ---------------------------------------------------------------------------
// K1: count in-degree per dst (cursor pre-zeroed by hipMemsetAsync)
// ---------------------------------------------------------------------------
__global__ __launch_bounds__(256) void count_kernel(const int* __restrict__ ei,
                                                    int* __restrict__ cursor,
                                                    int N, int E) {
    int e = blockIdx.x * 256 + threadIdx.x;
    if (e < E) {
        int d = ei[E + e];
        if ((unsigned)d < (unsigned)N) atomicAdd(&cursor[d], 1);
    }
}

// ---------------------------------------------------------------------------
// K2: single-block exclusive scan of (deg+1) -> rowptr, cursor=rowptr copy.
// 1024 threads -> 49 chunks for N=50000 (vs 196 at 256 threads).
// The +1 accounts for the self loop (replaces the old init kernel).
// ---------------------------------------------------------------------------
__global__ __launch_bounds__(1024) void scan_kernel(int* __restrict__ cursor,
                                                    int* __restrict__ rowptr,
                                                    int N) {
    __shared__ int wsums[16];
    __shared__ int carry;
    int tid = threadIdx.x;
    if (tid == 0) carry = 0;
    __syncthreads();
    int nchunk = (N + 1023) / 1024;
    for (int c = 0; c < nchunk; ++c) {
        int i = c * 1024 + tid;
        int v = (i < N) ? cursor[i] + 1 : 0;
        int lane = tid & 63;
        int incl = v;
        #pragma unroll
        for (int o = 1; o < 64; o <<= 1) {
            int t = __shfl_up(incl, o, 64);
            if (lane >= o) incl += t;
        }
        int w = tid >> 6;
        if (lane == 63) wsums[w] = incl;
        __syncthreads();
        int woff = 0;
        #pragma unroll
        for (int j = 0; j < 16; ++j)
            if (j < w) woff += wsums[j];
        int excl = carry + woff + incl - v;
        if (i < N) { rowptr[i] = excl; cursor[i] = excl; }
        __syncthreads();
        if (tid == 0) {
            int t = 0;
            #pragma unroll
            for (int j = 0; j < 16; ++j) t += wsums[j];
            carry += t;
        }
        __syncthreads();
    }
    if (tid == 0) rowptr[N] = carry;
}

// ---------------------------------------------------------------------------
// K3: scatter edges (and self loops) into CSR src lists
// ---------------------------------------------------------------------------
__global__ __launch_bounds__(256) void scatter_kernel(const int* __restrict__ ei,
                                                      int* __restrict__ cursor,
                                                      int* __restrict__ srclist,
                                                      int N, int E) {
    int e = blockIdx.x * 256 + threadIdx.x;
    if (e < E) {
        int s = ei[e];
        int d = ei[E + e];
        if ((unsigned)s < (unsigned)N && (unsigned)d < (unsigned)N) {
            int pos = atomicAdd(&cursor[d], 1);
            srclist[pos] = s;
        }
    } else if (e < E + N) {
        int n = e - E;
        int pos = atomicAdd(&cursor[n], 1);
        srclist[pos] = n;
    }
}

// ---------------------------------------------------------------------------
// K4: SGEMM  h16[M,256](bf16) = x[M,256] @ W[256,256]   (fp32 compute)
// 64x64 tile per 256-thread block, 4x4 microtile per thread, BK=16.
// Epilogue converts to bf16 (RNE) -> halves all downstream gather traffic.
// ---------------------------------------------------------------------------
#define BM 64
#define BN 64
#define BK 16
__global__ __launch_bounds__(256) void gemm_kernel(const float* __restrict__ A,
                                                   const float* __restrict__ B,
                                                   unsigned short* __restrict__ h16,
                                                   int M) {
    __shared__ float As[BK][BM + 4];
    __shared__ float Bs[BK][BN];
    int tid = threadIdx.x;
    int tx = tid & 15;
    int ty = tid >> 4;
    int row0 = blockIdx.x * BM;
    int col0 = blockIdx.y * BN;

    float acc[4][4];
    #pragma unroll
    for (int i = 0; i < 4; ++i)
        #pragma unroll
        for (int j = 0; j < 4; ++j) acc[i][j] = 0.f;

    for (int k0 = 0; k0 < CH; k0 += BK) {
        #pragma unroll
        for (int i = tid; i < BM * BK; i += 256) {
            int r = i >> 4;
            int k = i & 15;
            int gr = row0 + r;
            As[k][r] = (gr < M) ? A[(size_t)gr * CH + k0 + k] : 0.f;
        }
        #pragma unroll
        for (int i = tid; i < BK * BN; i += 256) {
            int k = i >> 6;
            int cc = i & 63;
            Bs[k][cc] = B[(size_t)(k0 + k) * CH + col0 + cc];
        }
        __syncthreads();
        #pragma unroll
        for (int k = 0; k < BK; ++k) {
            float4 a4 = *reinterpret_cast<const float4*>(&As[k][ty * 4]);
            float4 b4 = *reinterpret_cast<const float4*>(&Bs[k][tx * 4]);
            float a[4] = {a4.x, a4.y, a4.z, a4.w};
            float b[4] = {b4.x, b4.y, b4.z, b4.w};
            #pragma unroll
            for (int i = 0; i < 4; ++i)
                #pragma unroll
                for (int j = 0; j < 4; ++j) acc[i][j] += a[i] * b[j];
        }
        __syncthreads();
    }

    #pragma unroll
    for (int i = 0; i < 4; ++i) {
        int gr = row0 + ty * 4 + i;
        if (gr < M) {
            ushort4 v;
            v.x = f2bf(acc[i][0]);
            v.y = f2bf(acc[i][1]);
            v.z = f2bf(acc[i][2]);
            v.w = f2bf(acc[i][3]);
            *reinterpret_cast<ushort4*>(&h16[(size_t)gr * CH + col0 + tx * 4]) = v;
        }
    }
}

// ---------------------------------------------------------------------------
// K5: attention scores from bf16 h. One block per node; wave = head.
// a_src stored as [N][4] floats (float4-aligned) for the aggregate's
// one-shot LDS staging.
// ---------------------------------------------------------------------------
__global__ __launch_bounds__(256) void attn_kernel(const unsigned short* __restrict__ h16,
                                                   const float* __restrict__ att_src,
                                                   const float* __restrict__ att_dst,
                                                   float* __restrict__ a_src,
                                                   float* __restrict__ a_dst,
                                                   int N) {
    int n = blockIdx.x;
    int tid = threadIdx.x;
    int hd = tid >> 6;
    int lane = tid & 63;
    float v = bf2f(h16[(size_t)n * CH + tid]);
    float s = v * att_src[tid];
    float d = v * att_dst[tid];
    #pragma unroll
    for (int o = 32; o > 0; o >>= 1) {
        s += __shfl_xor(s, o, 64);
        d += __shfl_xor(d, o, 64);
    }
    if (lane == 0) {
        a_src[n * HEADS + hd] = s;
        a_dst[n * HEADS + hd] = d;
    }
}

// ---------------------------------------------------------------------------
// K6: aggregate. One block per dst node, thread = output channel.
// Edge metadata (src idx + 4-head a_src) staged in LDS per chunk, then the
// h-row gather is unrolled x4 to keep 4 independent global loads in flight.
// No atomics anywhere; single coalesced row write.
// exp without max-subtraction: |alpha| < ~15 so fp32 exp cannot overflow and
// the softmax ratio is mathematically identical.
// ---------------------------------------------------------------------------
__global__ __launch_bounds__(256) void aggregate_kernel(const unsigned short* __restrict__ h16,
                                                        const float4* __restrict__ a_src4,
                                                        const float* __restrict__ a_dst,
                                                        const int* __restrict__ rowptr,
                                                        const int* __restrict__ srclist,
                                                        const float* __restrict__ bias,
                                                        float* __restrict__ out,
                                                        int N) {
    __shared__ int   s_src[MAXDEG];
    __shared__ float s_as[MAXDEG][4];
    int n = blockIdx.x;
    int tid = threadIdx.x;
    int hd = tid >> 6;
    int start = rowptr[n];
    int end = rowptr[n + 1];
    float ad = a_dst[n * HEADS + hd];
    float acc = 0.f;
    float denom = 0.f;

    for (int base = start; base < end; base += MAXDEG) {
        int cnt = min(end - base, MAXDEG);
        if (tid < cnt) {
            int s = srclist[base + tid];
            s_src[tid] = s;
            float4 a = a_src4[s];
            s_as[tid][0] = a.x; s_as[tid][1] = a.y;
            s_as[tid][2] = a.z; s_as[tid][3] = a.w;
        }
        __syncthreads();
        int i = 0;
        for (; i + 4 <= cnt; i += 4) {
            int s0 = s_src[i], s1 = s_src[i + 1], s2 = s_src[i + 2], s3 = s_src[i + 3];
            unsigned short u0 = h16[(size_t)s0 * CH + tid];
            unsigned short u1 = h16[(size_t)s1 * CH + tid];
            unsigned short u2 = h16[(size_t)s2 * CH + tid];
            unsigned short u3 = h16[(size_t)s3 * CH + tid];
            float al0 = s_as[i][hd] + ad;     al0 = (al0 >= 0.f) ? al0 : NEG_SLOPE * al0;
            float al1 = s_as[i + 1][hd] + ad; al1 = (al1 >= 0.f) ? al1 : NEG_SLOPE * al1;
            float al2 = s_as[i + 2][hd] + ad; al2 = (al2 >= 0.f) ? al2 : NEG_SLOPE * al2;
            float al3 = s_as[i + 3][hd] + ad; al3 = (al3 >= 0.f) ? al3 : NEG_SLOPE * al3;
            float e0 = __expf(al0), e1 = __expf(al1), e2 = __expf(al2), e3 = __expf(al3);
            denom += (e0 + e1) + (e2 + e3);
            acc += e0 * bf2f(u0) + e1 * bf2f(u1) + e2 * bf2f(u2) + e3 * bf2f(u3);
        }
        for (; i < cnt; ++i) {
            int s = s_src[i];
            unsigned short u = h16[(size_t)s * CH + tid];
            float al = s_as[i][hd] + ad;
            al = (al >= 0.f) ? al : NEG_SLOPE * al;
            float e = __expf(al);
            denom += e;
            acc += e * bf2f(u);
        }
        __syncthreads();
    }
    out[(size_t)n * CH + tid] = acc / (denom + 1e-16f) + bias[tid];
}

// ---------------------------------------------------------------------------
extern "C" void kernel_launch(void* const* d_in, const int* in_sizes, int n_in,
                              void* d_out, int out_size, void* d_ws, size_t ws_size,
                              hipStream_t stream) {
    const float* x       = (const float*)d_in[0];
    const int*   ei      = (const int*)d_in[1];
    const float* W       = (const float*)d_in[2];
    const float* att_src = (const float*)d_in[3];
    const float* att_dst = (const float*)d_in[4];
    const float* bias    = (const float*)d_in[5];
    float* out = (float*)d_out;

    int N = in_sizes[0] / CH;      // 50000
    int E = in_sizes[1] / 2;       // 800000

    auto align = [](size_t v) { return (v + 255) & ~(size_t)255; };
    char* ws = (char*)d_ws;
    size_t off = 0;
    unsigned short* h16 = (unsigned short*)(ws + off); off = align(off + (size_t)N * CH * 2);
    float* a_src  = (float*)(ws + off); off = align(off + (size_t)N * HEADS * 4);
    float* a_dst  = (float*)(ws + off); off = align(off + (size_t)N * HEADS * 4);
    int*   rowptr = (int*)(ws + off);   off = align(off + (size_t)(N + 1) * 4);
    int*   cursor = (int*)(ws + off);   off = align(off + (size_t)N * 4);
    int*   srclist= (int*)(ws + off);   off = align(off + (size_t)(E + N) * 4);

    // CSR build
    hipMemsetAsync(cursor, 0, (size_t)N * 4, stream);
    count_kernel<<<(E + 255) / 256, 256, 0, stream>>>(ei, cursor, N, E);
    scan_kernel<<<1, 1024, 0, stream>>>(cursor, rowptr, N);
    scatter_kernel<<<(E + N + 255) / 256, 256, 0, stream>>>(ei, cursor, srclist, N, E);

    // dense phase
    dim3 ggrid((N + BM - 1) / BM, CH / BN);
    gemm_kernel<<<ggrid, 256, 0, stream>>>(x, W, h16, N);
    attn_kernel<<<N, 256, 0, stream>>>(h16, att_src, att_dst, a_src, a_dst, N);

    // gather-aggregate
    aggregate_kernel<<<N, 256, 0, stream>>>(h16, (const float4*)a_src, a_dst,
                                            rowptr, srclist, bias, out, N);
}

// Round 3
// 357.319 us; speedup vs baseline: 1.7642x; 1.3336x over previous
//
#include <hip/hip_runtime.h>
#include <hip/hip_bf16.h>

#define HEADS 4
#define OUT_C 64
#define CH 256           // HEADS*OUT_C == IN_C == 256
#define NEG_SLOPE 0.2f
#define MAXDEG 128       // edge-chunk staged in LDS per dst node

typedef short short8 __attribute__((ext_vector_type(8)));
typedef float f32x4 __attribute__((ext_vector_type(4)));

__device__ inline float bf2f(unsigned short u) {
    return __uint_as_float(((unsigned)u) << 16);
}
__device__ inline unsigned short f2bf(float f) {
    __hip_bfloat16 b = __float2bfloat16(f);   // RNE
    return *reinterpret_cast<unsigned short*>(&b);
}

#define GLOAD_LDS16(g, l)                                                   \
    __builtin_amdgcn_global_load_lds(                                       \
        (const __attribute__((address_space(1))) void*)(g),                 \
        (__attribute__((address_space(3))) void*)(l), 16, 0, 0)

// ---------------------------------------------------------------------------
// K1: count in-degree per dst (cursor pre-zeroed by hipMemsetAsync)
// ---------------------------------------------------------------------------
__global__ __launch_bounds__(256) void count_kernel(const int* __restrict__ ei,
                                                    int* __restrict__ cursor,
                                                    int N, int E) {
    int e = blockIdx.x * 256 + threadIdx.x;
    if (e < E) {
        int d = ei[E + e];
        if ((unsigned)d < (unsigned)N) atomicAdd(&cursor[d], 1);
    }
}

// ---------------------------------------------------------------------------
// K2a/b/c: parallel 3-phase exclusive scan of (deg+1) -> rowptr (+cursor copy)
// replaces the single-block serial scan (~60 us -> ~15 us).
// ---------------------------------------------------------------------------
__global__ __launch_bounds__(256) void scan_p1(const int* __restrict__ deg,
                                               int* __restrict__ blocksum, int N) {
    __shared__ int ws[4];
    int t = threadIdx.x;
    int i = blockIdx.x * 256 + t;
    int v = (i < N) ? deg[i] + 1 : 0;
    #pragma unroll
    for (int o = 32; o > 0; o >>= 1) v += __shfl_xor(v, o, 64);
    if ((t & 63) == 0) ws[t >> 6] = v;
    __syncthreads();
    if (t == 0) blocksum[blockIdx.x] = ws[0] + ws[1] + ws[2] + ws[3];
}

__global__ __launch_bounds__(256) void scan_p2(const int* __restrict__ blocksum,
                                               int* __restrict__ blockoff,
                                               int* __restrict__ rowptrN, int SB) {
    __shared__ int ws[4];
    int t = threadIdx.x;
    int lane = t & 63, w = t >> 6;
    int v = (t < SB) ? blocksum[t] : 0;
    int incl = v;
    #pragma unroll
    for (int o = 1; o < 64; o <<= 1) {
        int x = __shfl_up(incl, o, 64);
        if (lane >= o) incl += x;
    }
    if (lane == 63) ws[w] = incl;
    __syncthreads();
    int off = 0;
    #pragma unroll
    for (int j = 0; j < 4; ++j) if (j < w) off += ws[j];
    int excl = off + incl - v;
    if (t < SB) blockoff[t] = excl;
    if (t == 255) rowptrN[0] = excl + v;   // grand total (SB<=256)
}

__global__ __launch_bounds__(256) void scan_p3(const int* __restrict__ deg,
                                               const int* __restrict__ blockoff,
                                               int* __restrict__ rowptr,
                                               int* __restrict__ cursor, int N) {
    __shared__ int ws[4];
    int t = threadIdx.x;
    int i = blockIdx.x * 256 + t;
    int lane = t & 63, w = t >> 6;
    int v = (i < N) ? deg[i] + 1 : 0;
    int incl = v;
    #pragma unroll
    for (int o = 1; o < 64; o <<= 1) {
        int x = __shfl_up(incl, o, 64);
        if (lane >= o) incl += x;
    }
    if (lane == 63) ws[w] = incl;
    __syncthreads();
    int off = 0;
    #pragma unroll
    for (int j = 0; j < 4; ++j) if (j < w) off += ws[j];
    int excl = blockoff[blockIdx.x] + off + incl - v;
    if (i < N) { rowptr[i] = excl; cursor[i] = excl; }
}

// ---------------------------------------------------------------------------
// K3: scatter edges (and self loops) into CSR src lists
// ---------------------------------------------------------------------------
__global__ __launch_bounds__(256) void scatter_kernel(const int* __restrict__ ei,
                                                      int* __restrict__ cursor,
                                                      int* __restrict__ srclist,
                                                      int N, int E) {
    int e = blockIdx.x * 256 + threadIdx.x;
    if (e < E) {
        int s = ei[e];
        int d = ei[E + e];
        if ((unsigned)s < (unsigned)N && (unsigned)d < (unsigned)N) {
            int pos = atomicAdd(&cursor[d], 1);
            srclist[pos] = s;
        }
    } else if (e < E + N) {
        int n = e - E;
        int pos = atomicAdd(&cursor[n], 1);
        srclist[pos] = n;
    }
}

// ---------------------------------------------------------------------------
// K4a: convert x fp32 -> bf16 (coalesced float4 -> ushort4)
// ---------------------------------------------------------------------------
__global__ __launch_bounds__(256) void xconv_kernel(const float4* __restrict__ x4,
                                                    ushort4* __restrict__ xb4,
                                                    int n4) {
    int i = blockIdx.x * 256 + threadIdx.x;
    if (i < n4) {
        float4 v = x4[i];
        ushort4 u;
        u.x = f2bf(v.x); u.y = f2bf(v.y); u.z = f2bf(v.z); u.w = f2bf(v.w);
        xb4[i] = u;
    }
}

// ---------------------------------------------------------------------------
// K4b: W[256][256] -> Wt bf16 [n][k]  (transpose + convert; tiny)
// ---------------------------------------------------------------------------
__global__ __launch_bounds__(256) void wconv_kernel(const float* __restrict__ W,
                                                    unsigned short* __restrict__ wt) {
    int n = blockIdx.x;          // 256 blocks
    int k = threadIdx.x;         // 256 threads
    wt[n * 256 + k] = f2bf(W[k * 256 + n]);
}

// ---------------------------------------------------------------------------
// K4: MFMA bf16 GEMM  h16[M,256] = xb[M,256] @ Wt^T   (fp32 accumulate)
// 128x64 tile / block (256 thr = 4 waves, each 32 rows x 64 cols = 8 mfma
// tiles of 16x16x32). BK=64. global_load_lds width-16 staging with XOR-chunk
// swizzle: LDS slot (row r, chunk cs) holds logical k-chunk cs^(r&7), which
// keeps the wave-uniform-base constraint AND makes frag ds_read_b128 2-way
// (free) instead of 16-way conflicted.
// ---------------------------------------------------------------------------
__global__ __launch_bounds__(256) void gemm_kernel(const unsigned short* __restrict__ xb,
                                                   const unsigned short* __restrict__ wt,
                                                   unsigned short* __restrict__ h16,
                                                   int M) {
    __shared__ unsigned short As[128 * 64];   // 16 KB
    __shared__ unsigned short Bs[64 * 64];    // 8 KB
    int tid = threadIdx.x;
    int w = tid >> 6, l = tid & 63;
    int quad = l >> 4, m16 = l & 15;
    int row0 = blockIdx.x * 128, col0 = blockIdx.y * 64;

    f32x4 acc[2][4];
    #pragma unroll
    for (int t = 0; t < 2; ++t)
        #pragma unroll
        for (int u = 0; u < 4; ++u) acc[t][u] = (f32x4)(0.f);

    for (int k0 = 0; k0 < CH; k0 += 64) {
        // stage A tile: 128 rows x 64 k  (1024 16B chunks, 4 issues)
        #pragma unroll
        for (int q = 0; q < 4; ++q) {
            int cslot = q * 256 + tid;
            int r = cslot >> 3, cs = cslot & 7;
            int j = cs ^ (r & 7);
            int grow = row0 + r; if (grow > M - 1) grow = M - 1;
            const unsigned short* gp = xb + (size_t)grow * CH + k0 + j * 8;
            GLOAD_LDS16(gp, As + cslot * 8);
        }
        // stage B tile: 64 cols x 64 k   (512 chunks, 2 issues)
        #pragma unroll
        for (int q = 0; q < 2; ++q) {
            int cslot = q * 256 + tid;
            int r = cslot >> 3, cs = cslot & 7;
            int j = cs ^ (r & 7);
            const unsigned short* gp = wt + (size_t)(col0 + r) * CH + k0 + j * 8;
            GLOAD_LDS16(gp, Bs + cslot * 8);
        }
        __syncthreads();
        #pragma unroll
        for (int ks = 0; ks < 2; ++ks) {
            short8 af[2], bf[4];
            int j = ks * 4 + quad;
            #pragma unroll
            for (int t = 0; t < 2; ++t) {
                int r = w * 32 + t * 16 + m16;
                int cs = j ^ (r & 7);
                af[t] = *reinterpret_cast<const short8*>(As + (r * 8 + cs) * 8);
            }
            #pragma unroll
            for (int u = 0; u < 4; ++u) {
                int c = u * 16 + m16;
                int cs = j ^ (c & 7);
                bf[u] = *reinterpret_cast<const short8*>(Bs + (c * 8 + cs) * 8);
            }
            #pragma unroll
            for (int t = 0; t < 2; ++t)
                #pragma unroll
                for (int u = 0; u < 4; ++u)
                    acc[t][u] = __builtin_amdgcn_mfma_f32_16x16x32_bf16(
                        af[t], bf[u], acc[t][u], 0, 0, 0);
        }
        __syncthreads();
    }

    // epilogue: C/D layout col=lane&15, row=quad*4+reg
    #pragma unroll
    for (int t = 0; t < 2; ++t) {
        #pragma unroll
        for (int reg = 0; reg < 4; ++reg) {
            int row = row0 + w * 32 + t * 16 + quad * 4 + reg;
            if (row < M) {
                #pragma unroll
                for (int u = 0; u < 4; ++u) {
                    int col = col0 + u * 16 + m16;
                    h16[(size_t)row * CH + col] = f2bf(acc[t][u][reg]);
                }
            }
        }
    }
}

// ---------------------------------------------------------------------------
// K5: attention scores from bf16 h. One block per node; wave = head.
// ---------------------------------------------------------------------------
__global__ __launch_bounds__(256) void attn_kernel(const unsigned short* __restrict__ h16,
                                                   const float* __restrict__ att_src,
                                                   const float* __restrict__ att_dst,
                                                   float* __restrict__ a_src,
                                                   float* __restrict__ a_dst,
                                                   int N) {
    int n = blockIdx.x;
    int tid = threadIdx.x;
    int hd = tid >> 6;
    int lane = tid & 63;
    float v = bf2f(h16[(size_t)n * CH + tid]);
    float s = v * att_src[tid];
    float d = v * att_dst[tid];
    #pragma unroll
    for (int o = 32; o > 0; o >>= 1) {
        s += __shfl_xor(s, o, 64);
        d += __shfl_xor(d, o, 64);
    }
    if (lane == 0) {
        a_src[n * HEADS + hd] = s;
        a_dst[n * HEADS + hd] = d;
    }
}

// ---------------------------------------------------------------------------
// K6: aggregate. One block per dst node, thread = output channel.
// ---------------------------------------------------------------------------
__global__ __launch_bounds__(256) void aggregate_kernel(const unsigned short* __restrict__ h16,
                                                        const float4* __restrict__ a_src4,
                                                        const float* __restrict__ a_dst,
                                                        const int* __restrict__ rowptr,
                                                        const int* __restrict__ srclist,
                                                        const float* __restrict__ bias,
                                                        float* __restrict__ out,
                                                        int N) {
    __shared__ int   s_src[MAXDEG];
    __shared__ float s_as[MAXDEG][4];
    int n = blockIdx.x;
    int tid = threadIdx.x;
    int hd = tid >> 6;
    int start = rowptr[n];
    int end = rowptr[n + 1];
    float ad = a_dst[n * HEADS + hd];
    float acc = 0.f;
    float denom = 0.f;

    for (int base = start; base < end; base += MAXDEG) {
        int cnt = min(end - base, MAXDEG);
        if (tid < cnt) {
            int s = srclist[base + tid];
            s_src[tid] = s;
            float4 a = a_src4[s];
            s_as[tid][0] = a.x; s_as[tid][1] = a.y;
            s_as[tid][2] = a.z; s_as[tid][3] = a.w;
        }
        __syncthreads();
        int i = 0;
        for (; i + 4 <= cnt; i += 4) {
            int s0 = s_src[i], s1 = s_src[i + 1], s2 = s_src[i + 2], s3 = s_src[i + 3];
            unsigned short u0 = h16[(size_t)s0 * CH + tid];
            unsigned short u1 = h16[(size_t)s1 * CH + tid];
            unsigned short u2 = h16[(size_t)s2 * CH + tid];
            unsigned short u3 = h16[(size_t)s3 * CH + tid];
            float al0 = s_as[i][hd] + ad;     al0 = (al0 >= 0.f) ? al0 : NEG_SLOPE * al0;
            float al1 = s_as[i + 1][hd] + ad; al1 = (al1 >= 0.f) ? al1 : NEG_SLOPE * al1;
            float al2 = s_as[i + 2][hd] + ad; al2 = (al2 >= 0.f) ? al2 : NEG_SLOPE * al2;
            float al3 = s_as[i + 3][hd] + ad; al3 = (al3 >= 0.f) ? al3 : NEG_SLOPE * al3;
            float e0 = __expf(al0), e1 = __expf(al1), e2 = __expf(al2), e3 = __expf(al3);
            denom += (e0 + e1) + (e2 + e3);
            acc += e0 * bf2f(u0) + e1 * bf2f(u1) + e2 * bf2f(u2) + e3 * bf2f(u3);
        }
        for (; i < cnt; ++i) {
            int s = s_src[i];
            unsigned short u = h16[(size_t)s * CH + tid];
            float al = s_as[i][hd] + ad;
            al = (al >= 0.f) ? al : NEG_SLOPE * al;
            float e = __expf(al);
            denom += e;
            acc += e * bf2f(u);
        }
        __syncthreads();
    }
    out[(size_t)n * CH + tid] = acc / (denom + 1e-16f) + bias[tid];
}

// ---------------------------------------------------------------------------
extern "C" void kernel_launch(void* const* d_in, const int* in_sizes, int n_in,
                              void* d_out, int out_size, void* d_ws, size_t ws_size,
                              hipStream_t stream) {
    const float* x       = (const float*)d_in[0];
    const int*   ei      = (const int*)d_in[1];
    const float* W       = (const float*)d_in[2];
    const float* att_src = (const float*)d_in[3];
    const float* att_dst = (const float*)d_in[4];
    const float* bias    = (const float*)d_in[5];
    float* out = (float*)d_out;

    int N = in_sizes[0] / CH;      // 50000
    int E = in_sizes[1] / 2;       // 800000
    int SB = (N + 255) / 256;      // 196 scan blocks

    auto align = [](size_t v) { return (v + 255) & ~(size_t)255; };
    char* ws = (char*)d_ws;
    size_t off = 0;
    unsigned short* h16 = (unsigned short*)(ws + off); off = align(off + (size_t)N * CH * 2);
    unsigned short* xb  = (unsigned short*)(ws + off); off = align(off + (size_t)N * CH * 2);
    unsigned short* wt  = (unsigned short*)(ws + off); off = align(off + (size_t)CH * CH * 2);
    float* a_src  = (float*)(ws + off); off = align(off + (size_t)N * HEADS * 4);
    float* a_dst  = (float*)(ws + off); off = align(off + (size_t)N * HEADS * 4);
    int*   rowptr = (int*)(ws + off);   off = align(off + (size_t)(N + 1) * 4);
    int*   cursor = (int*)(ws + off);   off = align(off + (size_t)N * 4);
    int*   bsum   = (int*)(ws + off);   off = align(off + (size_t)SB * 4);
    int*   boff   = (int*)(ws + off);   off = align(off + (size_t)SB * 4);
    int*   srclist= (int*)(ws + off);   off = align(off + (size_t)(E + N) * 4);

    // CSR build
    hipMemsetAsync(cursor, 0, (size_t)N * 4, stream);
    count_kernel<<<(E + 255) / 256, 256, 0, stream>>>(ei, cursor, N, E);
    scan_p1<<<SB, 256, 0, stream>>>(cursor, bsum, N);
    scan_p2<<<1, 256, 0, stream>>>(bsum, boff, rowptr + N, SB);
    scan_p3<<<SB, 256, 0, stream>>>(cursor, boff, rowptr, cursor, N);
    scatter_kernel<<<(E + N + 255) / 256, 256, 0, stream>>>(ei, cursor, srclist, N, E);

    // dense phase: convert inputs to bf16, then MFMA GEMM
    int n4 = N * CH / 4;
    xconv_kernel<<<(n4 + 255) / 256, 256, 0, stream>>>((const float4*)x, (ushort4*)xb, n4);
    wconv_kernel<<<256, 256, 0, stream>>>(W, wt);
    dim3 ggrid((N + 127) / 128, CH / 64);
    gemm_kernel<<<ggrid, 256, 0, stream>>>(xb, wt, h16, N);
    attn_kernel<<<N, 256, 0, stream>>>(h16, att_src, att_dst, a_src, a_dst, N);

    // gather-aggregate
    aggregate_kernel<<<N, 256, 0, stream>>>(h16, (const float4*)a_src, a_dst,
                                            rowptr, srclist, bias, out, N);
}

// Round 4
// 312.957 us; speedup vs baseline: 2.0142x; 1.1417x over previous
//
#include <hip/hip_runtime.h>
#include <hip/hip_bf16.h>

#define HEADS 4
#define OUT_C 64
#define CH 256           // HEADS*OUT_C == IN_C == 256
#define NEG_SLOPE 0.2f
#define MAXDEG 128       // edge-chunk staged in LDS per dst node

typedef short short8 __attribute__((ext_vector_type(8)));
typedef float f32x4 __attribute__((ext_vector_type(4)));

__device__ inline float bf2f(unsigned short u) {
    return __uint_as_float(((unsigned)u) << 16);
}
__device__ inline float bflo(unsigned int u) {       // low bf16 of packed pair
    return __uint_as_float(u << 16);
}
__device__ inline float bfhi(unsigned int u) {       // high bf16 of packed pair
    return __uint_as_float(u & 0xFFFF0000u);
}
__device__ inline unsigned short f2bf(float f) {
    __hip_bfloat16 b = __float2bfloat16(f);   // RNE
    return *reinterpret_cast<unsigned short*>(&b);
}

#define GLOAD_LDS16(g, l)                                                   \
    __builtin_amdgcn_global_load_lds(                                       \
        (const __attribute__((address_space(1))) void*)(g),                 \
        (__attribute__((address_space(3))) void*)(l), 16, 0, 0)

// ---------------------------------------------------------------------------
// K1: count in-degree per dst (cursor pre-zeroed by hipMemsetAsync).
// int4 edge reads: 4 edges/thread.
// ---------------------------------------------------------------------------
__global__ __launch_bounds__(256) void count_kernel(const int4* __restrict__ dst4,
                                                    int* __restrict__ cursor,
                                                    int N, int E4) {
    int i = blockIdx.x * 256 + threadIdx.x;
    if (i < E4) {
        int4 d = dst4[i];
        if ((unsigned)d.x < (unsigned)N) atomicAdd(&cursor[d.x], 1);
        if ((unsigned)d.y < (unsigned)N) atomicAdd(&cursor[d.y], 1);
        if ((unsigned)d.z < (unsigned)N) atomicAdd(&cursor[d.z], 1);
        if ((unsigned)d.w < (unsigned)N) atomicAdd(&cursor[d.w], 1);
    }
}

// ---------------------------------------------------------------------------
// K2a/b/c: parallel 3-phase exclusive scan of (deg+1) -> rowptr (+cursor copy)
// ---------------------------------------------------------------------------
__global__ __launch_bounds__(256) void scan_p1(const int* __restrict__ deg,
                                               int* __restrict__ blocksum, int N) {
    __shared__ int ws[4];
    int t = threadIdx.x;
    int i = blockIdx.x * 256 + t;
    int v = (i < N) ? deg[i] + 1 : 0;
    #pragma unroll
    for (int o = 32; o > 0; o >>= 1) v += __shfl_xor(v, o, 64);
    if ((t & 63) == 0) ws[t >> 6] = v;
    __syncthreads();
    if (t == 0) blocksum[blockIdx.x] = ws[0] + ws[1] + ws[2] + ws[3];
}

__global__ __launch_bounds__(256) void scan_p2(const int* __restrict__ blocksum,
                                               int* __restrict__ blockoff,
                                               int* __restrict__ rowptrN, int SB) {
    __shared__ int ws[4];
    int t = threadIdx.x;
    int lane = t & 63, w = t >> 6;
    int v = (t < SB) ? blocksum[t] : 0;
    int incl = v;
    #pragma unroll
    for (int o = 1; o < 64; o <<= 1) {
        int x = __shfl_up(incl, o, 64);
        if (lane >= o) incl += x;
    }
    if (lane == 63) ws[w] = incl;
    __syncthreads();
    int off = 0;
    #pragma unroll
    for (int j = 0; j < 4; ++j) if (j < w) off += ws[j];
    int excl = off + incl - v;
    if (t < SB) blockoff[t] = excl;
    if (t == 255) rowptrN[0] = excl + v;   // grand total (SB<=256)
}

__global__ __launch_bounds__(256) void scan_p3(const int* __restrict__ deg,
                                               const int* __restrict__ blockoff,
                                               int* __restrict__ rowptr,
                                               int* __restrict__ cursor, int N) {
    __shared__ int ws[4];
    int t = threadIdx.x;
    int i = blockIdx.x * 256 + t;
    int lane = t & 63, w = t >> 6;
    int v = (i < N) ? deg[i] + 1 : 0;
    int incl = v;
    #pragma unroll
    for (int o = 1; o < 64; o <<= 1) {
        int x = __shfl_up(incl, o, 64);
        if (lane >= o) incl += x;
    }
    if (lane == 63) ws[w] = incl;
    __syncthreads();
    int off = 0;
    #pragma unroll
    for (int j = 0; j < 4; ++j) if (j < w) off += ws[j];
    int excl = blockoff[blockIdx.x] + off + incl - v;
    if (i < N) { rowptr[i] = excl; cursor[i] = excl; }
}

// ---------------------------------------------------------------------------
// K3: scatter edges (and self loops) into CSR src lists
// ---------------------------------------------------------------------------
__global__ __launch_bounds__(256) void scatter_kernel(const int* __restrict__ ei,
                                                      int* __restrict__ cursor,
                                                      int* __restrict__ srclist,
                                                      int N, int E) {
    int e = blockIdx.x * 256 + threadIdx.x;
    if (e < E) {
        int s = ei[e];
        int d = ei[E + e];
        if ((unsigned)s < (unsigned)N && (unsigned)d < (unsigned)N) {
            int pos = atomicAdd(&cursor[d], 1);
            srclist[pos] = s;
        }
    } else if (e < E + N) {
        int n = e - E;
        int pos = atomicAdd(&cursor[n], 1);
        srclist[pos] = n;
    }
}

// ---------------------------------------------------------------------------
// K4a: fused conversions. Blocks [0, nxb): x fp32 -> bf16 (float4->ushort4).
// Blocks [nxb, nxb+256): W transpose+convert -> wt[n][k] bf16.
// ---------------------------------------------------------------------------
__global__ __launch_bounds__(256) void conv_kernel(const float4* __restrict__ x4,
                                                   ushort4* __restrict__ xb4, int n4,
                                                   const float* __restrict__ W,
                                                   unsigned short* __restrict__ wt,
                                                   int nxb) {
    int b = blockIdx.x;
    if (b < nxb) {
        int i = b * 256 + threadIdx.x;
        if (i < n4) {
            float4 v = x4[i];
            ushort4 u;
            u.x = f2bf(v.x); u.y = f2bf(v.y); u.z = f2bf(v.z); u.w = f2bf(v.w);
            xb4[i] = u;
        }
    } else {
        int n = b - nxb;
        int k = threadIdx.x;
        wt[n * 256 + k] = f2bf(W[k * 256 + n]);
    }
}

// ---------------------------------------------------------------------------
// K4: MFMA bf16 GEMM  h16[M,256] = xb[M,256] @ Wt^T   (fp32 accumulate)
// 128x64 tile / block, BK=64, global_load_lds w=16, XOR-chunk swizzle.
// ---------------------------------------------------------------------------
__global__ __launch_bounds__(256) void gemm_kernel(const unsigned short* __restrict__ xb,
                                                   const unsigned short* __restrict__ wt,
                                                   unsigned short* __restrict__ h16,
                                                   int M) {
    __shared__ unsigned short As[128 * 64];   // 16 KB
    __shared__ unsigned short Bs[64 * 64];    // 8 KB
    int tid = threadIdx.x;
    int w = tid >> 6, l = tid & 63;
    int quad = l >> 4, m16 = l & 15;
    int row0 = blockIdx.x * 128, col0 = blockIdx.y * 64;

    f32x4 acc[2][4];
    #pragma unroll
    for (int t = 0; t < 2; ++t)
        #pragma unroll
        for (int u = 0; u < 4; ++u) acc[t][u] = (f32x4)(0.f);

    for (int k0 = 0; k0 < CH; k0 += 64) {
        #pragma unroll
        for (int q = 0; q < 4; ++q) {
            int cslot = q * 256 + tid;
            int r = cslot >> 3, cs = cslot & 7;
            int j = cs ^ (r & 7);
            int grow = row0 + r; if (grow > M - 1) grow = M - 1;
            const unsigned short* gp = xb + (size_t)grow * CH + k0 + j * 8;
            GLOAD_LDS16(gp, As + cslot * 8);
        }
        #pragma unroll
        for (int q = 0; q < 2; ++q) {
            int cslot = q * 256 + tid;
            int r = cslot >> 3, cs = cslot & 7;
            int j = cs ^ (r & 7);
            const unsigned short* gp = wt + (size_t)(col0 + r) * CH + k0 + j * 8;
            GLOAD_LDS16(gp, Bs + cslot * 8);
        }
        __syncthreads();
        #pragma unroll
        for (int ks = 0; ks < 2; ++ks) {
            short8 af[2], bf[4];
            int j = ks * 4 + quad;
            #pragma unroll
            for (int t = 0; t < 2; ++t) {
                int r = w * 32 + t * 16 + m16;
                int cs = j ^ (r & 7);
                af[t] = *reinterpret_cast<const short8*>(As + (r * 8 + cs) * 8);
            }
            #pragma unroll
            for (int u = 0; u < 4; ++u) {
                int c = u * 16 + m16;
                int cs = j ^ (c & 7);
                bf[u] = *reinterpret_cast<const short8*>(Bs + (c * 8 + cs) * 8);
            }
            #pragma unroll
            for (int t = 0; t < 2; ++t)
                #pragma unroll
                for (int u = 0; u < 4; ++u)
                    acc[t][u] = __builtin_amdgcn_mfma_f32_16x16x32_bf16(
                        af[t], bf[u], acc[t][u], 0, 0, 0);
        }
        __syncthreads();
    }

    #pragma unroll
    for (int t = 0; t < 2; ++t) {
        #pragma unroll
        for (int reg = 0; reg < 4; ++reg) {
            int row = row0 + w * 32 + t * 16 + quad * 4 + reg;
            if (row < M) {
                #pragma unroll
                for (int u = 0; u < 4; ++u) {
                    int col = col0 + u * 16 + m16;
                    h16[(size_t)row * CH + col] = f2bf(acc[t][u][reg]);
                }
            }
        }
    }
}

// ---------------------------------------------------------------------------
// K5: attention scores. Wave per node (4 nodes/block); lane owns 4 channels
// (uint2 load = 512 B per wave-instr). Head = lane>>4; reduce within 16 lanes.
// ---------------------------------------------------------------------------
__global__ __launch_bounds__(256) void attn_kernel(const unsigned short* __restrict__ h16,
                                                   const float4* __restrict__ att_src4,
                                                   const float4* __restrict__ att_dst4,
                                                   float* __restrict__ a_src,
                                                   float* __restrict__ a_dst,
                                                   int N) {
    int w = threadIdx.x >> 6, lane = threadIdx.x & 63;
    int n = blockIdx.x * 4 + w;
    if (n >= N) return;
    uint2 u = *((const uint2*)(h16 + (size_t)n * CH) + lane);
    float4 as = att_src4[lane];
    float4 ds = att_dst4[lane];
    float f0 = bflo(u.x), f1 = bfhi(u.x), f2 = bflo(u.y), f3 = bfhi(u.y);
    float s = f0 * as.x + f1 * as.y + f2 * as.z + f3 * as.w;
    float d = f0 * ds.x + f1 * ds.y + f2 * ds.z + f3 * ds.w;
    #pragma unroll
    for (int o = 8; o > 0; o >>= 1) {
        s += __shfl_xor(s, o, 64);
        d += __shfl_xor(d, o, 64);
    }
    if ((lane & 15) == 0) {
        int hd = lane >> 4;
        a_src[n * HEADS + hd] = s;
        a_dst[n * HEADS + hd] = d;
    }
}

// ---------------------------------------------------------------------------
// K6: aggregate. One block per dst node. Staging computes the 4 per-head exp
// weights ONCE per edge (kills the 64x-redundant exp in the old inner loop).
// Inner loop: half-wave (32 lanes) per edge, lane owns 8 channels via one
// global_load_dwordx4 (512 B/instr); 8 edges in flight per block.
// Cross-slot reduction via stride-9-padded LDS. No atomics anywhere.
// exp without max-subtraction: |alpha| < ~15, fp32 exp safe, ratio identical.
// ---------------------------------------------------------------------------
__global__ __launch_bounds__(256) void aggregate_kernel(const unsigned short* __restrict__ h16,
                                                        const float4* __restrict__ a_src4,
                                                        const float4* __restrict__ a_dst4,
                                                        const int* __restrict__ rowptr,
                                                        const int* __restrict__ srclist,
                                                        const float* __restrict__ bias,
                                                        float* __restrict__ out,
                                                        int N) {
    __shared__ int   s_src[MAXDEG];
    __shared__ float s_w[MAXDEG][4];
    __shared__ float s_red[8][32][9];   // stride-9 pad: conflict-free epilogue
    __shared__ float s_dn[8][4];
    int n = blockIdx.x;
    int tid = threadIdx.x;
    int w = tid >> 6, lane = tid & 63;
    int half = lane >> 5, l32 = lane & 31;
    int head = l32 >> 3;                // lane's 8 channels sit in one head
    int slot = w * 2 + half;            // 0..7 edge-slots per block
    int start = rowptr[n], end = rowptr[n + 1];

    float facc[8];
    #pragma unroll
    for (int j = 0; j < 8; ++j) facc[j] = 0.f;
    float denom = 0.f;

    float4 ad = a_dst4[n];

    for (int base = start; base < end; base += MAXDEG) {
        int cnt = min(end - base, MAXDEG);
        __syncthreads();
        if (tid < cnt) {
            int s = srclist[base + tid];
            s_src[tid] = s;
            float4 a = a_src4[s];
            float al0 = a.x + ad.x; al0 = (al0 >= 0.f) ? al0 : NEG_SLOPE * al0;
            float al1 = a.y + ad.y; al1 = (al1 >= 0.f) ? al1 : NEG_SLOPE * al1;
            float al2 = a.z + ad.z; al2 = (al2 >= 0.f) ? al2 : NEG_SLOPE * al2;
            float al3 = a.w + ad.w; al3 = (al3 >= 0.f) ? al3 : NEG_SLOPE * al3;
            s_w[tid][0] = __expf(al0);
            s_w[tid][1] = __expf(al1);
            s_w[tid][2] = __expf(al2);
            s_w[tid][3] = __expf(al3);
        }
        __syncthreads();
        for (int i = slot; i < cnt; i += 8) {
            int s = s_src[i];
            float e = s_w[i][head];
            uint4 u = *((const uint4*)(h16 + (size_t)s * CH) + l32);
            denom += e;
            facc[0] += e * bflo(u.x);
            facc[1] += e * bfhi(u.x);
            facc[2] += e * bflo(u.y);
            facc[3] += e * bfhi(u.y);
            facc[4] += e * bflo(u.z);
            facc[5] += e * bfhi(u.z);
            facc[6] += e * bflo(u.w);
            facc[7] += e * bfhi(u.w);
        }
    }

    #pragma unroll
    for (int j = 0; j < 8; ++j) s_red[slot][l32][j] = facc[j];
    if ((l32 & 7) == 0) s_dn[slot][head] = denom;
    __syncthreads();

    float v = 0.f, dn = 0.f;
    #pragma unroll
    for (int p = 0; p < 8; ++p) {
        v  += s_red[p][tid >> 3][tid & 7];
        dn += s_dn[p][tid >> 6];
    }
    out[(size_t)n * CH + tid] = v / (dn + 1e-16f) + bias[tid];
}

// ---------------------------------------------------------------------------
extern "C" void kernel_launch(void* const* d_in, const int* in_sizes, int n_in,
                              void* d_out, int out_size, void* d_ws, size_t ws_size,
                              hipStream_t stream) {
    const float* x       = (const float*)d_in[0];
    const int*   ei      = (const int*)d_in[1];
    const float* W       = (const float*)d_in[2];
    const float* att_src = (const float*)d_in[3];
    const float* att_dst = (const float*)d_in[4];
    const float* bias    = (const float*)d_in[5];
    float* out = (float*)d_out;

    int N = in_sizes[0] / CH;      // 50000
    int E = in_sizes[1] / 2;       // 800000
    int SB = (N + 255) / 256;      // scan blocks

    auto align = [](size_t v) { return (v + 255) & ~(size_t)255; };
    char* ws = (char*)d_ws;
    size_t off = 0;
    unsigned short* h16 = (unsigned short*)(ws + off); off = align(off + (size_t)N * CH * 2);
    unsigned short* xb  = (unsigned short*)(ws + off); off = align(off + (size_t)N * CH * 2);
    unsigned short* wt  = (unsigned short*)(ws + off); off = align(off + (size_t)CH * CH * 2);
    float* a_src  = (float*)(ws + off); off = align(off + (size_t)N * HEADS * 4);
    float* a_dst  = (float*)(ws + off); off = align(off + (size_t)N * HEADS * 4);
    int*   rowptr = (int*)(ws + off);   off = align(off + (size_t)(N + 1) * 4);
    int*   cursor = (int*)(ws + off);   off = align(off + (size_t)N * 4);
    int*   bsum   = (int*)(ws + off);   off = align(off + (size_t)SB * 4);
    int*   boff   = (int*)(ws + off);   off = align(off + (size_t)SB * 4);
    int*   srclist= (int*)(ws + off);   off = align(off + (size_t)(E + N) * 4);

    // CSR build
    hipMemsetAsync(cursor, 0, (size_t)N * 4, stream);
    int E4 = E / 4;
    count_kernel<<<(E4 + 255) / 256, 256, 0, stream>>>((const int4*)(ei + E), cursor, N, E4);
    scan_p1<<<SB, 256, 0, stream>>>(cursor, bsum, N);
    scan_p2<<<1, 256, 0, stream>>>(bsum, boff, rowptr + N, SB);
    scan_p3<<<SB, 256, 0, stream>>>(cursor, boff, rowptr, cursor, N);
    scatter_kernel<<<(E + N + 255) / 256, 256, 0, stream>>>(ei, cursor, srclist, N, E);

    // dense phase: convert inputs to bf16 (x + W fused), then MFMA GEMM
    int n4 = N * CH / 4;
    int nxb = (n4 + 255) / 256;
    conv_kernel<<<nxb + 256, 256, 0, stream>>>((const float4*)x, (ushort4*)xb, n4, W, wt, nxb);
    dim3 ggrid((N + 127) / 128, CH / 64);
    gemm_kernel<<<ggrid, 256, 0, stream>>>(xb, wt, h16, N);
    attn_kernel<<<(N + 3) / 4, 256, 0, stream>>>(h16, (const float4*)att_src,
                                                 (const float4*)att_dst, a_src, a_dst, N);

    // gather-aggregate
    aggregate_kernel<<<N, 256, 0, stream>>>(h16, (const float4*)a_src, (const float4*)a_dst,
                                            rowptr, srclist, bias, out, N);
}

// Round 5
// 304.787 us; speedup vs baseline: 2.0682x; 1.0268x over previous
//
#include <hip/hip_runtime.h>
#include <hip/hip_bf16.h>

#define HEADS 4
#define OUT_C 64
#define CH 256           // HEADS*OUT_C == IN_C == 256
#define NEG_SLOPE 0.2f
#define MAXDEG 128       // edge-chunk staged in LDS per dst node

typedef short short8 __attribute__((ext_vector_type(8)));
typedef float f32x4 __attribute__((ext_vector_type(4)));

__device__ inline float bf2f(unsigned short u) {
    return __uint_as_float(((unsigned)u) << 16);
}
__device__ inline float bflo(unsigned int u) {
    return __uint_as_float(u << 16);
}
__device__ inline float bfhi(unsigned int u) {
    return __uint_as_float(u & 0xFFFF0000u);
}
__device__ inline unsigned short f2bf(float f) {
    __hip_bfloat16 b = __float2bfloat16(f);   // RNE
    return *reinterpret_cast<unsigned short*>(&b);
}

#define GLOAD_LDS16(g, l)                                                   \
    __builtin_amdgcn_global_load_lds(                                       \
        (const __attribute__((address_space(1))) void*)(g),                 \
        (__attribute__((address_space(3))) void*)(l), 16, 0, 0)

// ---------------------------------------------------------------------------
// K1: count in-degree per dst (cursor pre-zeroed by hipMemsetAsync).
// ---------------------------------------------------------------------------
__global__ __launch_bounds__(256) void count_kernel(const int4* __restrict__ dst4,
                                                    int* __restrict__ cursor,
                                                    int N, int E4) {
    int i = blockIdx.x * 256 + threadIdx.x;
    if (i < E4) {
        int4 d = dst4[i];
        if ((unsigned)d.x < (unsigned)N) atomicAdd(&cursor[d.x], 1);
        if ((unsigned)d.y < (unsigned)N) atomicAdd(&cursor[d.y], 1);
        if ((unsigned)d.z < (unsigned)N) atomicAdd(&cursor[d.z], 1);
        if ((unsigned)d.w < (unsigned)N) atomicAdd(&cursor[d.w], 1);
    }
}

// ---------------------------------------------------------------------------
// K2a/b/c: parallel 3-phase exclusive scan of (deg+1) -> rowptr (+cursor copy)
// ---------------------------------------------------------------------------
__global__ __launch_bounds__(256) void scan_p1(const int* __restrict__ deg,
                                               int* __restrict__ blocksum, int N) {
    __shared__ int ws[4];
    int t = threadIdx.x;
    int i = blockIdx.x * 256 + t;
    int v = (i < N) ? deg[i] + 1 : 0;
    #pragma unroll
    for (int o = 32; o > 0; o >>= 1) v += __shfl_xor(v, o, 64);
    if ((t & 63) == 0) ws[t >> 6] = v;
    __syncthreads();
    if (t == 0) blocksum[blockIdx.x] = ws[0] + ws[1] + ws[2] + ws[3];
}

__global__ __launch_bounds__(256) void scan_p2(const int* __restrict__ blocksum,
                                               int* __restrict__ blockoff,
                                               int* __restrict__ rowptrN, int SB) {
    __shared__ int ws[4];
    int t = threadIdx.x;
    int lane = t & 63, w = t >> 6;
    int v = (t < SB) ? blocksum[t] : 0;
    int incl = v;
    #pragma unroll
    for (int o = 1; o < 64; o <<= 1) {
        int x = __shfl_up(incl, o, 64);
        if (lane >= o) incl += x;
    }
    if (lane == 63) ws[w] = incl;
    __syncthreads();
    int off = 0;
    #pragma unroll
    for (int j = 0; j < 4; ++j) if (j < w) off += ws[j];
    int excl = off + incl - v;
    if (t < SB) blockoff[t] = excl;
    if (t == 255) rowptrN[0] = excl + v;   // grand total (SB<=256)
}

__global__ __launch_bounds__(256) void scan_p3(const int* __restrict__ deg,
                                               const int* __restrict__ blockoff,
                                               int* __restrict__ rowptr,
                                               int* __restrict__ cursor, int N) {
    __shared__ int ws[4];
    int t = threadIdx.x;
    int i = blockIdx.x * 256 + t;
    int lane = t & 63, w = t >> 6;
    int v = (i < N) ? deg[i] + 1 : 0;
    int incl = v;
    #pragma unroll
    for (int o = 1; o < 64; o <<= 1) {
        int x = __shfl_up(incl, o, 64);
        if (lane >= o) incl += x;
    }
    if (lane == 63) ws[w] = incl;
    __syncthreads();
    int off = 0;
    #pragma unroll
    for (int j = 0; j < 4; ++j) if (j < w) off += ws[j];
    int excl = blockoff[blockIdx.x] + off + incl - v;
    if (i < N) { rowptr[i] = excl; cursor[i] = excl; }
}

// ---------------------------------------------------------------------------
// K3: scatter edges (and self loops) into CSR src lists
// ---------------------------------------------------------------------------
__global__ __launch_bounds__(256) void scatter_kernel(const int* __restrict__ ei,
                                                      int* __restrict__ cursor,
                                                      int* __restrict__ srclist,
                                                      int N, int E) {
    int e = blockIdx.x * 256 + threadIdx.x;
    if (e < E) {
        int s = ei[e];
        int d = ei[E + e];
        if ((unsigned)s < (unsigned)N && (unsigned)d < (unsigned)N) {
            int pos = atomicAdd(&cursor[d], 1);
            srclist[pos] = s;
        }
    } else if (e < E + N) {
        int n = e - E;
        int pos = atomicAdd(&cursor[n], 1);
        srclist[pos] = n;
    }
}

// ---------------------------------------------------------------------------
// K4a: fused conversions. Blocks [0, nxb): x fp32 -> bf16.
// Blocks [nxb, nxb+256): W transpose+convert -> wt[n][k] bf16.
// ---------------------------------------------------------------------------
__global__ __launch_bounds__(256) void conv_kernel(const float4* __restrict__ x4,
                                                   ushort4* __restrict__ xb4, int n4,
                                                   const float* __restrict__ W,
                                                   unsigned short* __restrict__ wt,
                                                   int nxb) {
    int b = blockIdx.x;
    if (b < nxb) {
        int i = b * 256 + threadIdx.x;
        if (i < n4) {
            float4 v = x4[i];
            ushort4 u;
            u.x = f2bf(v.x); u.y = f2bf(v.y); u.z = f2bf(v.z); u.w = f2bf(v.w);
            xb4[i] = u;
        }
    } else {
        int n = b - nxb;
        int k = threadIdx.x;
        wt[n * 256 + k] = f2bf(W[k * 256 + n]);
    }
}

// ---------------------------------------------------------------------------
// K4: MFMA bf16 GEMM  h16[M,256] = xb[M,256] @ Wt^T  + fused attn epilogue.
// 128x64 tile / block, BK=64, global_load_lds w=16, XOR-chunk swizzle.
// blockIdx.y == head index (64 cols == one head), so the C fragments hold
// everything needed for a_src/a_dst: 4 FMAs + xor-shfl reduce over the 16
// lanes that share a row, lane m16==0 writes. Kills the separate attn pass.
// ---------------------------------------------------------------------------
__global__ __launch_bounds__(256) void gemm_kernel(const unsigned short* __restrict__ xb,
                                                   const unsigned short* __restrict__ wt,
                                                   const float* __restrict__ att_src,
                                                   const float* __restrict__ att_dst,
                                                   unsigned short* __restrict__ h16,
                                                   float* __restrict__ a_src,
                                                   float* __restrict__ a_dst,
                                                   int M) {
    __shared__ unsigned short As[128 * 64];   // 16 KB
    __shared__ unsigned short Bs[64 * 64];    // 8 KB
    int tid = threadIdx.x;
    int w = tid >> 6, l = tid & 63;
    int quad = l >> 4, m16 = l & 15;
    int row0 = blockIdx.x * 128, col0 = blockIdx.y * 64;
    int hd = blockIdx.y;

    f32x4 acc[2][4];
    #pragma unroll
    for (int t = 0; t < 2; ++t)
        #pragma unroll
        for (int u = 0; u < 4; ++u) acc[t][u] = (f32x4)(0.f);

    for (int k0 = 0; k0 < CH; k0 += 64) {
        #pragma unroll
        for (int q = 0; q < 4; ++q) {
            int cslot = q * 256 + tid;
            int r = cslot >> 3, cs = cslot & 7;
            int j = cs ^ (r & 7);
            int grow = row0 + r; if (grow > M - 1) grow = M - 1;
            const unsigned short* gp = xb + (size_t)grow * CH + k0 + j * 8;
            GLOAD_LDS16(gp, As + cslot * 8);
        }
        #pragma unroll
        for (int q = 0; q < 2; ++q) {
            int cslot = q * 256 + tid;
            int r = cslot >> 3, cs = cslot & 7;
            int j = cs ^ (r & 7);
            const unsigned short* gp = wt + (size_t)(col0 + r) * CH + k0 + j * 8;
            GLOAD_LDS16(gp, Bs + cslot * 8);
        }
        __syncthreads();
        #pragma unroll
        for (int ks = 0; ks < 2; ++ks) {
            short8 af[2], bf[4];
            int j = ks * 4 + quad;
            #pragma unroll
            for (int t = 0; t < 2; ++t) {
                int r = w * 32 + t * 16 + m16;
                int cs = j ^ (r & 7);
                af[t] = *reinterpret_cast<const short8*>(As + (r * 8 + cs) * 8);
            }
            #pragma unroll
            for (int u = 0; u < 4; ++u) {
                int c = u * 16 + m16;
                int cs = j ^ (c & 7);
                bf[u] = *reinterpret_cast<const short8*>(Bs + (c * 8 + cs) * 8);
            }
            #pragma unroll
            for (int t = 0; t < 2; ++t)
                #pragma unroll
                for (int u = 0; u < 4; ++u)
                    acc[t][u] = __builtin_amdgcn_mfma_f32_16x16x32_bf16(
                        af[t], bf[u], acc[t][u], 0, 0, 0);
        }
        __syncthreads();
    }

    // attn vectors for this head, this lane's 4 columns
    float asr[4], adr[4];
    #pragma unroll
    for (int u = 0; u < 4; ++u) {
        asr[u] = att_src[hd * 64 + u * 16 + m16];
        adr[u] = att_dst[hd * 64 + u * 16 + m16];
    }

    // epilogue: C/D layout col=lane&15, row=quad*4+reg
    #pragma unroll
    for (int t = 0; t < 2; ++t) {
        #pragma unroll
        for (int reg = 0; reg < 4; ++reg) {
            int row = row0 + w * 32 + t * 16 + quad * 4 + reg;
            float sv = 0.f, dv = 0.f;
            #pragma unroll
            for (int u = 0; u < 4; ++u) {
                float c = acc[t][u][reg];
                sv += c * asr[u];
                dv += c * adr[u];
            }
            #pragma unroll
            for (int o = 8; o > 0; o >>= 1) {
                sv += __shfl_xor(sv, o, 64);
                dv += __shfl_xor(dv, o, 64);
            }
            if (row < M) {
                #pragma unroll
                for (int u = 0; u < 4; ++u) {
                    int col = col0 + u * 16 + m16;
                    h16[(size_t)row * CH + col] = f2bf(acc[t][u][reg]);
                }
                if (m16 == 0) {
                    a_src[row * HEADS + hd] = sv;
                    a_dst[row * HEADS + hd] = dv;
                }
            }
        }
    }
}

// ---------------------------------------------------------------------------
// K6: aggregate. One block per dst node. Per-edge exp weights computed once
// during staging (s_w padded to stride 5: conflict-free). Inner loop: half-
// wave per edge, lane owns 8 channels (global_load_dwordx4), unrolled x2 so
// each thread keeps 2 independent gathers in flight (latency hiding).
// ---------------------------------------------------------------------------
__global__ __launch_bounds__(256) void aggregate_kernel(const unsigned short* __restrict__ h16,
                                                        const float4* __restrict__ a_src4,
                                                        const float4* __restrict__ a_dst4,
                                                        const int* __restrict__ rowptr,
                                                        const int* __restrict__ srclist,
                                                        const float* __restrict__ bias,
                                                        float* __restrict__ out,
                                                        int N) {
    __shared__ int   s_src[MAXDEG];
    __shared__ float s_w[MAXDEG][5];    // stride-5 pad: conflict-free staging
    __shared__ float s_red[8][32][9];   // stride-9 pad: conflict-free epilogue
    __shared__ float s_dn[8][4];
    int n = blockIdx.x;
    int tid = threadIdx.x;
    int w = tid >> 6, lane = tid & 63;
    int half = lane >> 5, l32 = lane & 31;
    int head = l32 >> 3;
    int slot = w * 2 + half;            // 0..7 edge-slots per block
    int start = rowptr[n], end = rowptr[n + 1];

    float facc[8];
    #pragma unroll
    for (int j = 0; j < 8; ++j) facc[j] = 0.f;
    float denom = 0.f;

    float4 ad = a_dst4[n];

    for (int base = start; base < end; base += MAXDEG) {
        int cnt = min(end - base, MAXDEG);
        __syncthreads();
        if (tid < cnt) {
            int s = srclist[base + tid];
            s_src[tid] = s;
            float4 a = a_src4[s];
            float al0 = a.x + ad.x; al0 = (al0 >= 0.f) ? al0 : NEG_SLOPE * al0;
            float al1 = a.y + ad.y; al1 = (al1 >= 0.f) ? al1 : NEG_SLOPE * al1;
            float al2 = a.z + ad.z; al2 = (al2 >= 0.f) ? al2 : NEG_SLOPE * al2;
            float al3 = a.w + ad.w; al3 = (al3 >= 0.f) ? al3 : NEG_SLOPE * al3;
            s_w[tid][0] = __expf(al0);
            s_w[tid][1] = __expf(al1);
            s_w[tid][2] = __expf(al2);
            s_w[tid][3] = __expf(al3);
        }
        __syncthreads();
        int i = slot;
        for (; i + 8 < cnt; i += 16) {
            int s0 = s_src[i], s1 = s_src[i + 8];
            float e0 = s_w[i][head], e1 = s_w[i + 8][head];
            uint4 u0 = *((const uint4*)(h16 + (size_t)s0 * CH) + l32);
            uint4 u1 = *((const uint4*)(h16 + (size_t)s1 * CH) + l32);
            denom += e0 + e1;
            facc[0] += e0 * bflo(u0.x) + e1 * bflo(u1.x);
            facc[1] += e0 * bfhi(u0.x) + e1 * bfhi(u1.x);
            facc[2] += e0 * bflo(u0.y) + e1 * bflo(u1.y);
            facc[3] += e0 * bfhi(u0.y) + e1 * bfhi(u1.y);
            facc[4] += e0 * bflo(u0.z) + e1 * bflo(u1.z);
            facc[5] += e0 * bfhi(u0.z) + e1 * bfhi(u1.z);
            facc[6] += e0 * bflo(u0.w) + e1 * bflo(u1.w);
            facc[7] += e0 * bfhi(u0.w) + e1 * bfhi(u1.w);
        }
        if (i < cnt) {
            int s = s_src[i];
            float e = s_w[i][head];
            uint4 u = *((const uint4*)(h16 + (size_t)s * CH) + l32);
            denom += e;
            facc[0] += e * bflo(u.x);
            facc[1] += e * bfhi(u.x);
            facc[2] += e * bflo(u.y);
            facc[3] += e * bfhi(u.y);
            facc[4] += e * bflo(u.z);
            facc[5] += e * bfhi(u.z);
            facc[6] += e * bflo(u.w);
            facc[7] += e * bfhi(u.w);
        }
    }

    #pragma unroll
    for (int j = 0; j < 8; ++j) s_red[slot][l32][j] = facc[j];
    if ((l32 & 7) == 0) s_dn[slot][head] = denom;
    __syncthreads();

    float v = 0.f, dn = 0.f;
    #pragma unroll
    for (int p = 0; p < 8; ++p) {
        v  += s_red[p][tid >> 3][tid & 7];
        dn += s_dn[p][tid >> 6];
    }
    out[(size_t)n * CH + tid] = v / (dn + 1e-16f) + bias[tid];
}

// ---------------------------------------------------------------------------
extern "C" void kernel_launch(void* const* d_in, const int* in_sizes, int n_in,
                              void* d_out, int out_size, void* d_ws, size_t ws_size,
                              hipStream_t stream) {
    const float* x       = (const float*)d_in[0];
    const int*   ei      = (const int*)d_in[1];
    const float* W       = (const float*)d_in[2];
    const float* att_src = (const float*)d_in[3];
    const float* att_dst = (const float*)d_in[4];
    const float* bias    = (const float*)d_in[5];
    float* out = (float*)d_out;

    int N = in_sizes[0] / CH;      // 50000
    int E = in_sizes[1] / 2;       // 800000
    int SB = (N + 255) / 256;      // scan blocks

    auto align = [](size_t v) { return (v + 255) & ~(size_t)255; };
    char* ws = (char*)d_ws;
    size_t off = 0;
    unsigned short* h16 = (unsigned short*)(ws + off); off = align(off + (size_t)N * CH * 2);
    unsigned short* xb  = (unsigned short*)(ws + off); off = align(off + (size_t)N * CH * 2);
    unsigned short* wt  = (unsigned short*)(ws + off); off = align(off + (size_t)CH * CH * 2);
    float* a_src  = (float*)(ws + off); off = align(off + (size_t)N * HEADS * 4);
    float* a_dst  = (float*)(ws + off); off = align(off + (size_t)N * HEADS * 4);
    int*   rowptr = (int*)(ws + off);   off = align(off + (size_t)(N + 1) * 4);
    int*   cursor = (int*)(ws + off);   off = align(off + (size_t)N * 4);
    int*   bsum   = (int*)(ws + off);   off = align(off + (size_t)SB * 4);
    int*   boff   = (int*)(ws + off);   off = align(off + (size_t)SB * 4);
    int*   srclist= (int*)(ws + off);   off = align(off + (size_t)(E + N) * 4);

    // CSR build
    hipMemsetAsync(cursor, 0, (size_t)N * 4, stream);
    int E4 = E / 4;
    count_kernel<<<(E4 + 255) / 256, 256, 0, stream>>>((const int4*)(ei + E), cursor, N, E4);
    scan_p1<<<SB, 256, 0, stream>>>(cursor, bsum, N);
    scan_p2<<<1, 256, 0, stream>>>(bsum, boff, rowptr + N, SB);
    scan_p3<<<SB, 256, 0, stream>>>(cursor, boff, rowptr, cursor, N);
    scatter_kernel<<<(E + N + 255) / 256, 256, 0, stream>>>(ei, cursor, srclist, N, E);

    // dense phase: convert inputs to bf16, then MFMA GEMM (+fused attn)
    int n4 = N * CH / 4;
    int nxb = (n4 + 255) / 256;
    conv_kernel<<<nxb + 256, 256, 0, stream>>>((const float4*)x, (ushort4*)xb, n4, W, wt, nxb);
    dim3 ggrid((N + 127) / 128, CH / 64);
    gemm_kernel<<<ggrid, 256, 0, stream>>>(xb, wt, att_src, att_dst, h16, a_src, a_dst, N);

    // gather-aggregate
    aggregate_kernel<<<N, 256, 0, stream>>>(h16, (const float4*)a_src, (const float4*)a_dst,
                                            rowptr, srclist, bias, out, N);
}

// Round 6
// 290.483 us; speedup vs baseline: 2.1701x; 1.0492x over previous
//
#include <hip/hip_runtime.h>
#include <hip/hip_bf16.h>

#define HEADS 4
#define OUT_C 64
#define CH 256           // HEADS*OUT_C == IN_C == 256
#define NEG_SLOPE 0.2f

typedef short short8 __attribute__((ext_vector_type(8)));
typedef float f32x4 __attribute__((ext_vector_type(4)));

__device__ inline float bflo(unsigned int u) {
    return __uint_as_float(u << 16);
}
__device__ inline float bfhi(unsigned int u) {
    return __uint_as_float(u & 0xFFFF0000u);
}
__device__ inline unsigned short f2bf(float f) {
    __hip_bfloat16 b = __float2bfloat16(f);   // RNE
    return *reinterpret_cast<unsigned short*>(&b);
}

#define GLOAD_LDS16(g, l)                                                   \
    __builtin_amdgcn_global_load_lds(                                       \
        (const __attribute__((address_space(1))) void*)(g),                 \
        (__attribute__((address_space(3))) void*)(l), 16, 0, 0)

// ---------------------------------------------------------------------------
// K1: count in-degree per dst (cursor pre-zeroed by hipMemsetAsync).
// ---------------------------------------------------------------------------
__global__ __launch_bounds__(256) void count_kernel(const int4* __restrict__ dst4,
                                                    int* __restrict__ cursor,
                                                    int N, int E4) {
    int i = blockIdx.x * 256 + threadIdx.x;
    if (i < E4) {
        int4 d = dst4[i];
        if ((unsigned)d.x < (unsigned)N) atomicAdd(&cursor[d.x], 1);
        if ((unsigned)d.y < (unsigned)N) atomicAdd(&cursor[d.y], 1);
        if ((unsigned)d.z < (unsigned)N) atomicAdd(&cursor[d.z], 1);
        if ((unsigned)d.w < (unsigned)N) atomicAdd(&cursor[d.w], 1);
    }
}

// ---------------------------------------------------------------------------
// K2a/b/c: parallel 3-phase exclusive scan of (deg+1) -> rowptr (+cursor copy)
// ---------------------------------------------------------------------------
__global__ __launch_bounds__(256) void scan_p1(const int* __restrict__ deg,
                                               int* __restrict__ blocksum, int N) {
    __shared__ int ws[4];
    int t = threadIdx.x;
    int i = blockIdx.x * 256 + t;
    int v = (i < N) ? deg[i] + 1 : 0;
    #pragma unroll
    for (int o = 32; o > 0; o >>= 1) v += __shfl_xor(v, o, 64);
    if ((t & 63) == 0) ws[t >> 6] = v;
    __syncthreads();
    if (t == 0) blocksum[blockIdx.x] = ws[0] + ws[1] + ws[2] + ws[3];
}

__global__ __launch_bounds__(256) void scan_p2(const int* __restrict__ blocksum,
                                               int* __restrict__ blockoff,
                                               int* __restrict__ rowptrN, int SB) {
    __shared__ int ws[4];
    int t = threadIdx.x;
    int lane = t & 63, w = t >> 6;
    int v = (t < SB) ? blocksum[t] : 0;
    int incl = v;
    #pragma unroll
    for (int o = 1; o < 64; o <<= 1) {
        int x = __shfl_up(incl, o, 64);
        if (lane >= o) incl += x;
    }
    if (lane == 63) ws[w] = incl;
    __syncthreads();
    int off = 0;
    #pragma unroll
    for (int j = 0; j < 4; ++j) if (j < w) off += ws[j];
    int excl = off + incl - v;
    if (t < SB) blockoff[t] = excl;
    if (t == 255) rowptrN[0] = excl + v;   // grand total (SB<=256)
}

__global__ __launch_bounds__(256) void scan_p3(const int* __restrict__ deg,
                                               const int* __restrict__ blockoff,
                                               int* __restrict__ rowptr,
                                               int* __restrict__ cursor, int N) {
    __shared__ int ws[4];
    int t = threadIdx.x;
    int i = blockIdx.x * 256 + t;
    int lane = t & 63, w = t >> 6;
    int v = (i < N) ? deg[i] + 1 : 0;
    int incl = v;
    #pragma unroll
    for (int o = 1; o < 64; o <<= 1) {
        int x = __shfl_up(incl, o, 64);
        if (lane >= o) incl += x;
    }
    if (lane == 63) ws[w] = incl;
    __syncthreads();
    int off = 0;
    #pragma unroll
    for (int j = 0; j < 4; ++j) if (j < w) off += ws[j];
    int excl = blockoff[blockIdx.x] + off + incl - v;
    if (i < N) { rowptr[i] = excl; cursor[i] = excl; }
}

// ---------------------------------------------------------------------------
// K3: scatter edges (int4 = 4 edges/thread) and self loops into CSR src lists
// ---------------------------------------------------------------------------
__global__ __launch_bounds__(256) void scatter_kernel(const int* __restrict__ ei,
                                                      int* __restrict__ cursor,
                                                      int* __restrict__ srclist,
                                                      int N, int E) {
    int i = blockIdx.x * 256 + threadIdx.x;
    int E4 = E >> 2;
    if (i < E4) {
        int4 s4 = ((const int4*)ei)[i];
        int4 d4 = ((const int4*)(ei + E))[i];
        if ((unsigned)s4.x < (unsigned)N && (unsigned)d4.x < (unsigned)N)
            srclist[atomicAdd(&cursor[d4.x], 1)] = s4.x;
        if ((unsigned)s4.y < (unsigned)N && (unsigned)d4.y < (unsigned)N)
            srclist[atomicAdd(&cursor[d4.y], 1)] = s4.y;
        if ((unsigned)s4.z < (unsigned)N && (unsigned)d4.z < (unsigned)N)
            srclist[atomicAdd(&cursor[d4.z], 1)] = s4.z;
        if ((unsigned)s4.w < (unsigned)N && (unsigned)d4.w < (unsigned)N)
            srclist[atomicAdd(&cursor[d4.w], 1)] = s4.w;
    } else if (i < E4 + N) {
        int n = i - E4;
        srclist[atomicAdd(&cursor[n], 1)] = n;
    }
}

// ---------------------------------------------------------------------------
// K4a: fused conversions. Blocks [0, nxb): x fp32 -> bf16.
// Blocks [nxb, nxb+256): W transpose+convert -> wt[n][k] bf16.
// ---------------------------------------------------------------------------
__global__ __launch_bounds__(256) void conv_kernel(const float4* __restrict__ x4,
                                                   ushort4* __restrict__ xb4, int n4,
                                                   const float* __restrict__ W,
                                                   unsigned short* __restrict__ wt,
                                                   int nxb) {
    int b = blockIdx.x;
    if (b < nxb) {
        int i = b * 256 + threadIdx.x;
        if (i < n4) {
            float4 v = x4[i];
            ushort4 u;
            u.x = f2bf(v.x); u.y = f2bf(v.y); u.z = f2bf(v.z); u.w = f2bf(v.w);
            xb4[i] = u;
        }
    } else {
        int n = b - nxb;
        int k = threadIdx.x;
        wt[n * 256 + k] = f2bf(W[k * 256 + n]);
    }
}

// ---------------------------------------------------------------------------
// K4: MFMA bf16 GEMM  h16[M,256] = xb[M,256] @ Wt^T  + fused attn epilogue.
// 128x64 tile / block, BK=64, global_load_lds w=16, XOR-chunk swizzle.
// ---------------------------------------------------------------------------
__global__ __launch_bounds__(256) void gemm_kernel(const unsigned short* __restrict__ xb,
                                                   const unsigned short* __restrict__ wt,
                                                   const float* __restrict__ att_src,
                                                   const float* __restrict__ att_dst,
                                                   unsigned short* __restrict__ h16,
                                                   float* __restrict__ a_src,
                                                   float* __restrict__ a_dst,
                                                   int M) {
    __shared__ unsigned short As[128 * 64];   // 16 KB
    __shared__ unsigned short Bs[64 * 64];    // 8 KB
    int tid = threadIdx.x;
    int w = tid >> 6, l = tid & 63;
    int quad = l >> 4, m16 = l & 15;
    int row0 = blockIdx.x * 128, col0 = blockIdx.y * 64;
    int hd = blockIdx.y;

    f32x4 acc[2][4];
    #pragma unroll
    for (int t = 0; t < 2; ++t)
        #pragma unroll
        for (int u = 0; u < 4; ++u) acc[t][u] = (f32x4)(0.f);

    for (int k0 = 0; k0 < CH; k0 += 64) {
        #pragma unroll
        for (int q = 0; q < 4; ++q) {
            int cslot = q * 256 + tid;
            int r = cslot >> 3, cs = cslot & 7;
            int j = cs ^ (r & 7);
            int grow = row0 + r; if (grow > M - 1) grow = M - 1;
            const unsigned short* gp = xb + (size_t)grow * CH + k0 + j * 8;
            GLOAD_LDS16(gp, As + cslot * 8);
        }
        #pragma unroll
        for (int q = 0; q < 2; ++q) {
            int cslot = q * 256 + tid;
            int r = cslot >> 3, cs = cslot & 7;
            int j = cs ^ (r & 7);
            const unsigned short* gp = wt + (size_t)(col0 + r) * CH + k0 + j * 8;
            GLOAD_LDS16(gp, Bs + cslot * 8);
        }
        __syncthreads();
        #pragma unroll
        for (int ks = 0; ks < 2; ++ks) {
            short8 af[2], bf[4];
            int j = ks * 4 + quad;
            #pragma unroll
            for (int t = 0; t < 2; ++t) {
                int r = w * 32 + t * 16 + m16;
                int cs = j ^ (r & 7);
                af[t] = *reinterpret_cast<const short8*>(As + (r * 8 + cs) * 8);
            }
            #pragma unroll
            for (int u = 0; u < 4; ++u) {
                int c = u * 16 + m16;
                int cs = j ^ (c & 7);
                bf[u] = *reinterpret_cast<const short8*>(Bs + (c * 8 + cs) * 8);
            }
            #pragma unroll
            for (int t = 0; t < 2; ++t)
                #pragma unroll
                for (int u = 0; u < 4; ++u)
                    acc[t][u] = __builtin_amdgcn_mfma_f32_16x16x32_bf16(
                        af[t], bf[u], acc[t][u], 0, 0, 0);
        }
        __syncthreads();
    }

    // attn vectors for this head, this lane's 4 columns
    float asr[4], adr[4];
    #pragma unroll
    for (int u = 0; u < 4; ++u) {
        asr[u] = att_src[hd * 64 + u * 16 + m16];
        adr[u] = att_dst[hd * 64 + u * 16 + m16];
    }

    // epilogue: C/D layout col=lane&15, row=quad*4+reg
    #pragma unroll
    for (int t = 0; t < 2; ++t) {
        #pragma unroll
        for (int reg = 0; reg < 4; ++reg) {
            int row = row0 + w * 32 + t * 16 + quad * 4 + reg;
            float sv = 0.f, dv = 0.f;
            #pragma unroll
            for (int u = 0; u < 4; ++u) {
                float c = acc[t][u][reg];
                sv += c * asr[u];
                dv += c * adr[u];
            }
            #pragma unroll
            for (int o = 8; o > 0; o >>= 1) {
                sv += __shfl_xor(sv, o, 64);
                dv += __shfl_xor(dv, o, 64);
            }
            if (row < M) {
                #pragma unroll
                for (int u = 0; u < 4; ++u) {
                    int col = col0 + u * 16 + m16;
                    h16[(size_t)row * CH + col] = f2bf(acc[t][u][reg]);
                }
                if (m16 == 0) {
                    a_src[row * HEADS + hd] = sv;
                    a_dst[row * HEADS + hd] = dv;
                }
            }
        }
    }
}

// ---------------------------------------------------------------------------
// K6: aggregate — wave-per-node, ZERO LDS, ZERO barriers.
// Each wave owns one dst node. Edges processed in 16-edge chunks:
//   staging: lane-group g=lane>>2 owns edge g; lane g*4+h computes the exp
//            weight of head h for that edge (register-resident).
//   inner:   half-wave (32 lanes) processes 8 of the 16 edges; per edge the
//            src idx and this lane's head-weight arrive via dynamic __shfl
//            (ds_bpermute); h-row gathered as one 512B global_load_dwordx4
//            per half-wave, 8 independent loads in flight (unrolled).
//   epilogue: one shfl_xor(32) per accumulator, direct float4 stores.
// exp without max-subtraction: |alpha| < ~15, fp32 exp safe, ratio identical.
// ---------------------------------------------------------------------------
__global__ __launch_bounds__(256) void aggregate_kernel(const unsigned short* __restrict__ h16,
                                                        const float4* __restrict__ a_src4,
                                                        const float4* __restrict__ a_dst4,
                                                        const int* __restrict__ rowptr,
                                                        const int* __restrict__ srclist,
                                                        const float* __restrict__ bias,
                                                        float* __restrict__ out,
                                                        int N) {
    int tid = threadIdx.x;
    int w = tid >> 6, lane = tid & 63;
    int half = lane >> 5, l32 = lane & 31;
    int headC = l32 >> 3;            // head of this lane's 8 channels
    int g = lane >> 2;               // staging edge slot 0..15
    int headS = lane & 3;            // staging head
    int n = blockIdx.x * 4 + w;
    if (n >= N) return;

    int start = rowptr[n], end = rowptr[n + 1];
    float4 ad = a_dst4[n];
    float adS = headS == 0 ? ad.x : headS == 1 ? ad.y : headS == 2 ? ad.z : ad.w;

    float facc[8];
    #pragma unroll
    for (int j = 0; j < 8; ++j) facc[j] = 0.f;
    float denom = 0.f;

    for (int base = start; base < end; base += 16) {
        int cnt = min(end - base, 16);
        // ---- staging (registers only) ----
        int sg = (g < cnt) ? srclist[base + g] : 0;
        float4 a = a_src4[sg];
        float av = headS == 0 ? a.x : headS == 1 ? a.y : headS == 2 ? a.z : a.w;
        float al = av + adS;
        al = (al >= 0.f) ? al : NEG_SLOPE * al;
        float ew = __expf(al);
        // ---- gather: my half processes edges [half*8, half*8+8) ----
        #pragma unroll
        for (int j = 0; j < 8; ++j) {
            int i = half * 8 + j;
            if (i < cnt) {
                int s   = __shfl(sg, i * 4, 64);
                float e = __shfl(ew, i * 4 + headC, 64);
                uint4 u = *((const uint4*)(h16 + (size_t)s * CH) + l32);
                denom += e;
                facc[0] += e * bflo(u.x);
                facc[1] += e * bfhi(u.x);
                facc[2] += e * bflo(u.y);
                facc[3] += e * bfhi(u.y);
                facc[4] += e * bflo(u.z);
                facc[5] += e * bfhi(u.z);
                facc[6] += e * bflo(u.w);
                facc[7] += e * bfhi(u.w);
            }
        }
    }

    // combine halves (both halves end with the full per-head sums)
    #pragma unroll
    for (int j = 0; j < 8; ++j) facc[j] += __shfl_xor(facc[j], 32, 64);
    denom += __shfl_xor(denom, 32, 64);

    float inv = 1.f / (denom + 1e-16f);
    int cbase = l32 * 8 + half * 4;      // half0: ch 0..3, half1: ch 4..7 of octet
    float4 b4 = *(const float4*)(bias + cbase);
    float4 o4;
    o4.x = (half ? facc[4] : facc[0]) * inv + b4.x;
    o4.y = (half ? facc[5] : facc[1]) * inv + b4.y;
    o4.z = (half ? facc[6] : facc[2]) * inv + b4.z;
    o4.w = (half ? facc[7] : facc[3]) * inv + b4.w;
    *(float4*)(out + (size_t)n * CH + cbase) = o4;
}

// ---------------------------------------------------------------------------
extern "C" void kernel_launch(void* const* d_in, const int* in_sizes, int n_in,
                              void* d_out, int out_size, void* d_ws, size_t ws_size,
                              hipStream_t stream) {
    const float* x       = (const float*)d_in[0];
    const int*   ei      = (const int*)d_in[1];
    const float* W       = (const float*)d_in[2];
    const float* att_src = (const float*)d_in[3];
    const float* att_dst = (const float*)d_in[4];
    const float* bias    = (const float*)d_in[5];
    float* out = (float*)d_out;

    int N = in_sizes[0] / CH;      // 50000
    int E = in_sizes[1] / 2;       // 800000
    int SB = (N + 255) / 256;      // scan blocks

    auto align = [](size_t v) { return (v + 255) & ~(size_t)255; };
    char* ws = (char*)d_ws;
    size_t off = 0;
    unsigned short* h16 = (unsigned short*)(ws + off); off = align(off + (size_t)N * CH * 2);
    unsigned short* xb  = (unsigned short*)(ws + off); off = align(off + (size_t)N * CH * 2);
    unsigned short* wt  = (unsigned short*)(ws + off); off = align(off + (size_t)CH * CH * 2);
    float* a_src  = (float*)(ws + off); off = align(off + (size_t)N * HEADS * 4);
    float* a_dst  = (float*)(ws + off); off = align(off + (size_t)N * HEADS * 4);
    int*   rowptr = (int*)(ws + off);   off = align(off + (size_t)(N + 1) * 4);
    int*   cursor = (int*)(ws + off);   off = align(off + (size_t)N * 4);
    int*   bsum   = (int*)(ws + off);   off = align(off + (size_t)SB * 4);
    int*   boff   = (int*)(ws + off);   off = align(off + (size_t)SB * 4);
    int*   srclist= (int*)(ws + off);   off = align(off + (size_t)(E + N) * 4);

    // CSR build
    hipMemsetAsync(cursor, 0, (size_t)N * 4, stream);
    int E4 = E / 4;
    count_kernel<<<(E4 + 255) / 256, 256, 0, stream>>>((const int4*)(ei + E), cursor, N, E4);
    scan_p1<<<SB, 256, 0, stream>>>(cursor, bsum, N);
    scan_p2<<<1, 256, 0, stream>>>(bsum, boff, rowptr + N, SB);
    scan_p3<<<SB, 256, 0, stream>>>(cursor, boff, rowptr, cursor, N);
    scatter_kernel<<<(E4 + N + 255) / 256, 256, 0, stream>>>(ei, cursor, srclist, N, E);

    // dense phase: convert inputs to bf16, then MFMA GEMM (+fused attn)
    int n4 = N * CH / 4;
    int nxb = (n4 + 255) / 256;
    conv_kernel<<<nxb + 256, 256, 0, stream>>>((const float4*)x, (ushort4*)xb, n4, W, wt, nxb);
    dim3 ggrid((N + 127) / 128, CH / 64);
    gemm_kernel<<<ggrid, 256, 0, stream>>>(xb, wt, att_src, att_dst, h16, a_src, a_dst, N);

    // gather-aggregate
    aggregate_kernel<<<(N + 3) / 4, 256, 0, stream>>>(h16, (const float4*)a_src,
                                                      (const float4*)a_dst,
                                                      rowptr, srclist, bias, out, N);
}